// Round 3
// baseline (483.732 us; speedup 1.0000x reference)
//
#include <hip/hip_runtime.h>
#include <stdint.h>

typedef unsigned short u16;
typedef unsigned int u32;

typedef __bf16 bf16_t;
typedef bf16_t bf16x8 __attribute__((ext_vector_type(8)));
typedef float f32x4 __attribute__((ext_vector_type(4)));

__device__ __forceinline__ u16 f2b(float f) {
    u32 u = __builtin_bit_cast(u32, f);
    u += 0x7FFFu + ((u >> 16) & 1u);   // RNE
    return (u16)(u >> 16);
}
__device__ __forceinline__ float b2f(u16 h) {
    return __builtin_bit_cast(float, (u32)h << 16);
}

__device__ __forceinline__ void gld_lds16(const void* gptr, void* lptr) {
    __builtin_amdgcn_global_load_lds(
        (const __attribute__((address_space(1))) void*)gptr,
        (__attribute__((address_space(3))) void*)lptr,
        16, 0, 0);
}

// ---------------- f32 -> bf16 conversion ----------------
__global__ __launch_bounds__(256) void cvt_kernel(const float* __restrict__ s,
                                                  u16* __restrict__ d, int n4) {
    int i = blockIdx.x * 256 + threadIdx.x;
    const int stride = gridDim.x * 256;
    for (; i < n4; i += stride) {
        float4 v = reinterpret_cast<const float4*>(s)[i];
        uint2 o;
        o.x = (u32)f2b(v.x) | ((u32)f2b(v.y) << 16);
        o.y = (u32)f2b(v.z) | ((u32)f2b(v.w) << 16);
        reinterpret_cast<uint2*>(d)[i] = o;
    }
}

// ---------------- BT GEMM: C[M,N] = A[M,K] * B[N,K]^T, bf16 in, f32 acc ----
// 128x128 tile, BK=64, 4 waves (2x2 of 64x64), 16x16x32 MFMA.
// LDS: [128 rows][64 k] bf16 = 128 B/row, XOR-swizzled via pre-swizzled
// global source + swizzled ds_read (rule #21: both sides, same involution).
// EPI 0: store bf16                           (GEMM1: x_proj)
// EPI 1: elu+1 for cols<2048, store bf16      (GEMM2: qkv)
// EPI 2: add bf16 resid, store f32            (GEMM3: out proj + residual)
template <int EPI>
__global__ __launch_bounds__(256) void gemm_bt(
    const u16* __restrict__ A, const u16* __restrict__ Bw,
    float* __restrict__ outF, u16* __restrict__ outB,
    const u16* __restrict__ residB, int N, int K)
{
    __shared__ u16 As[8192];   // [128][64] bf16, 128 B per row
    __shared__ u16 Bs[8192];

    const int t = threadIdx.x;
    const int ntile = N >> 7;
    const int mt = blockIdx.x / ntile;
    const int nt = blockIdx.x - mt * ntile;
    const size_t brow = (size_t)mt << 7;
    const size_t bcol = (size_t)nt << 7;

    const int lane = t & 63;
    const int wv = t >> 6;
    const int wrow = (wv >> 1) << 6;
    const int wcol = (wv & 1) << 6;
    const int fr = lane & 15;
    const int fk = lane >> 4;
    const int swz = (fr & 7) << 4;

    f32x4 acc[4][4] = {};

    // staging: issue i covers rows i*32 + t/8, phys byte (t&7)*16
    const int srow = t >> 3;
    const int pb = (t & 7) << 4;

    for (int k0 = 0; k0 < K; k0 += 64) {
#pragma unroll
        for (int i = 0; i < 4; ++i) {
            const int row = (i << 5) + srow;
            const int kb = pb ^ ((row & 7) << 4);   // inverse-swizzled global source
            const u16* ga = A + (brow + row) * (size_t)K + (k0 + (kb >> 1));
            const u16* gb = Bw + (bcol + row) * (size_t)K + (k0 + (kb >> 1));
            gld_lds16(ga, As + (i << 11) + t * 8);  // linear LDS dest: row*128B + pb
            gld_lds16(gb, Bs + (i << 11) + t * 8);
        }
        __syncthreads();
#pragma unroll
        for (int ks = 0; ks < 2; ++ks) {
            const int col = ((ks << 6) | (fk << 4)) ^ swz;  // swizzled read (bytes)
            bf16x8 af[4], bfr[4];
#pragma unroll
            for (int i = 0; i < 4; ++i) {
                af[i]  = *(const bf16x8*)((const char*)As + (wrow + (i << 4) + fr) * 128 + col);
                bfr[i] = *(const bf16x8*)((const char*)Bs + (wcol + (i << 4) + fr) * 128 + col);
            }
#pragma unroll
            for (int i = 0; i < 4; ++i)
#pragma unroll
                for (int j = 0; j < 4; ++j)
                    acc[i][j] = __builtin_amdgcn_mfma_f32_16x16x32_bf16(
                        af[i], bfr[j], acc[i][j], 0, 0, 0);
        }
        __syncthreads();
    }

    // C/D mapping (m89-verified): col = lane&15, row = (lane>>4)*4 + reg
    const int r0 = (lane >> 4) << 2;
    const int c0 = lane & 15;
#pragma unroll
    for (int i = 0; i < 4; ++i) {
#pragma unroll
        for (int r = 0; r < 4; ++r) {
            const size_t grow = brow + wrow + (i << 4) + r0 + r;
#pragma unroll
            for (int j = 0; j < 4; ++j) {
                const size_t gcol = bcol + wcol + (j << 4) + c0;
                float v = acc[i][j][r];
                const size_t idx = grow * (size_t)N + gcol;
                if (EPI == 0) {
                    outB[idx] = f2b(v);
                } else if (EPI == 1) {
                    if (gcol < 2048) v = (v > 0.f) ? (v + 1.f) : __expf(v);  // elu+1
                    outB[idx] = f2b(v);
                } else {
                    outF[idx] = v + b2f(residB[idx]);
                }
            }
        }
    }
}

// ---------------- linear attention: partial kv (64x64) + ksum over L-split ----
// grid: bh(64) * split(8); qkv layout: [b][l][s(3)][h(16)][d(64)] bf16
__global__ __launch_bounds__(256) void attn_kv(
    const u16* __restrict__ qkvb, float* __restrict__ kvpart, float* __restrict__ kspart)
{
    __shared__ u16 kfs[2048];  // [32 l][64 d]
    __shared__ u16 vss[2048];
    __shared__ float ksp[4][64];
    const int t = threadIdx.x;
    const int bh = blockIdx.x >> 3;
    const int split = blockIdx.x & 7;
    const int b = bh >> 4, h = bh & 15;
    const size_t base = (size_t)b * (4096 * 3072) + h * 64;
    const int wv = t >> 6, lane = t & 63;
    const int lload = t >> 3, dload = (t & 7) << 3;

    float acc[16] = {};   // kv[wv*16 + i][lane]
    float ks = 0.f;

    for (int c = 0; c < 512; c += 32) {
        __syncthreads();
        const size_t l = (size_t)split * 512 + c + lload;
        *(uint4*)(kfs + lload * 64 + dload) = *(const uint4*)(qkvb + base + l * 3072 + 1024 + dload);
        *(uint4*)(vss + lload * 64 + dload) = *(const uint4*)(qkvb + base + l * 3072 + 2048 + dload);
        __syncthreads();
#pragma unroll 4
        for (int ll = 0; ll < 32; ++ll) {
            const float vv = b2f(vss[ll * 64 + lane]);
            const u32* kfu = (const u32*)(kfs + ll * 64 + (wv << 4));
#pragma unroll
            for (int p = 0; p < 8; ++p) {
                const u32 u = kfu[p];
                acc[2 * p]     += __builtin_bit_cast(float, u << 16) * vv;
                acc[2 * p + 1] += __builtin_bit_cast(float, u & 0xFFFF0000u) * vv;
            }
        }
        const int lb = wv << 3;
#pragma unroll
        for (int q = 0; q < 8; ++q) ks += b2f(kfs[(lb + q) * 64 + lane]);
    }
    ksp[wv][lane] = ks;
    const size_t obase = (size_t)blockIdx.x * 4096;
#pragma unroll
    for (int i = 0; i < 16; ++i)
        kvpart[obase + (size_t)((wv << 4) + i) * 64 + lane] = acc[i];
    __syncthreads();
    if (t < 64)
        kspart[(size_t)blockIdx.x * 64 + t] = ksp[0][t] + ksp[1][t] + ksp[2][t] + ksp[3][t];
}

// ---------------- reduce 8 partials ----------------
__global__ __launch_bounds__(256) void attn_red(
    const float* __restrict__ kvpart, const float* __restrict__ kspart,
    float* __restrict__ kv, float* __restrict__ ksum)
{
    const int bh = blockIdx.x;
    const int t = threadIdx.x;
    for (int e = t; e < 4096; e += 256) {
        float s = 0.f;
#pragma unroll
        for (int p = 0; p < 8; ++p) s += kvpart[((size_t)bh * 8 + p) * 4096 + e];
        kv[(size_t)bh * 4096 + e] = s;
    }
    if (t < 64) {
        float s = 0.f;
#pragma unroll
        for (int p = 0; p < 8; ++p) s += kspart[((size_t)bh * 8 + p) * 64 + t];
        ksum[(size_t)bh * 64 + t] = s;
    }
}

// ---------------- out = (qf @ kv) / (qf . ksum + 1e-8), store bf16 [b][h][l][d]
__global__ __launch_bounds__(256) void attn_out(
    const u16* __restrict__ qkvb, const float* __restrict__ kv,
    const float* __restrict__ ksum, u16* __restrict__ attnb)
{
    __shared__ float kvs[4096];
    __shared__ float kss[64];
    __shared__ u16 qs[4096];   // [64 l][64 d]
    const int t = threadIdx.x;
    const int bh = blockIdx.x >> 6;
    const int lblk = blockIdx.x & 63;
    const int b = bh >> 4, h = bh & 15;
    const size_t qbase = (size_t)b * (4096 * 3072) + h * 64;
    const int l0 = lblk << 6;

#pragma unroll
    for (int e = t * 4; e < 4096; e += 1024)
        *(float4*)(kvs + e) = *(const float4*)(kv + (size_t)bh * 4096 + e);
    if (t < 64) kss[t] = ksum[(size_t)bh * 64 + t];
    {
        const int lload = t >> 2;
        const int dload = (t & 3) << 4;
        const size_t src = qbase + (size_t)(l0 + lload) * 3072 + dload;
        *(uint4*)(qs + lload * 64 + dload)     = *(const uint4*)(qkvb + src);
        *(uint4*)(qs + lload * 64 + dload + 8) = *(const uint4*)(qkvb + src + 8);
    }
    __syncthreads();
    const int lloc = t >> 2;
    const int m0 = (t & 3) << 4;
    float o[16] = {};
    float nrm = 0.f;
#pragma unroll 4
    for (int d = 0; d < 64; ++d) {
        const float qv = b2f(qs[lloc * 64 + d]);
        nrm += qv * kss[d];
        const float4* kr = (const float4*)(kvs + d * 64 + m0);
#pragma unroll
        for (int j4 = 0; j4 < 4; ++j4) {
            const float4 kq = kr[j4];
            o[j4 * 4 + 0] += qv * kq.x;
            o[j4 * 4 + 1] += qv * kq.y;
            o[j4 * 4 + 2] += qv * kq.z;
            o[j4 * 4 + 3] += qv * kq.w;
        }
    }
    const float inv = 1.f / (nrm + 1e-8f);
    u32 pk[8];
#pragma unroll
    for (int j = 0; j < 8; ++j)
        pk[j] = (u32)f2b(o[2 * j] * inv) | ((u32)f2b(o[2 * j + 1] * inv) << 16);
    const size_t obase = ((size_t)bh * 4096 + l0 + lloc) * 64 + m0;
    uint4 w0 = {pk[0], pk[1], pk[2], pk[3]};
    uint4 w1 = {pk[4], pk[5], pk[6], pk[7]};
    *(uint4*)(attnb + obase) = w0;
    *(uint4*)(attnb + obase + 8) = w1;
}

// ---------------- RMS norm (in-place), one block per row of 1024 ----------------
__global__ __launch_bounds__(256) void rms_kernel(float* __restrict__ y,
                                                  const float* __restrict__ nw)
{
    __shared__ float red[4];
    const size_t row = blockIdx.x;
    const int t = threadIdx.x;
    float4 v = *(float4*)(y + row * 1024 + t * 4);
    float s = v.x * v.x + v.y * v.y + v.z * v.z + v.w * v.w;
#pragma unroll
    for (int off = 32; off > 0; off >>= 1) s += __shfl_down(s, off, 64);
    if ((t & 63) == 0) red[t >> 6] = s;
    __syncthreads();
    const float tot = red[0] + red[1] + red[2] + red[3];
    const float rms = rsqrtf(tot * (1.f / 1024.f) + 1.1920929e-7f);
    const float4 w = *(const float4*)(nw + t * 4);
    v.x *= rms * w.x; v.y *= rms * w.y; v.z *= rms * w.z; v.w *= rms * w.w;
    *(float4*)(y + row * 1024 + t * 4) = v;
}

extern "C" void kernel_launch(void* const* d_in, const int* in_sizes, int n_in,
                              void* d_out, int out_size, void* d_ws, size_t ws_size,
                              hipStream_t stream)
{
    const float* x     = (const float*)d_in[0];   // (4,4096,512)
    const float* w_in  = (const float*)d_in[1];   // (1024,512)
    const float* w_qkv = (const float*)d_in[2];   // (3072,1024)
    const float* w_out = (const float*)d_in[3];   // (1024,1024)
    const float* normw = (const float*)d_in[4];   // (1024,)
    float* out = (float*)d_out;                   // (4,4096,1024) f32

    char* ws = (char*)d_ws;
    size_t off = 0;
    auto alloc = [&](size_t bytes) {
        char* p = ws + off;
        off += (bytes + 255) & ~(size_t)255;
        return p;
    };
    // total ws usage ~194 MiB
    u16* xb    = (u16*)alloc(8388608ull * 2);    // x bf16                (16 MiB)
    u16* wib   = (u16*)alloc(524288ull * 2);     // w_in bf16             (1 MiB)
    u16* wqb   = (u16*)alloc(3145728ull * 2);    // w_qkv bf16            (6 MiB)
    u16* wob   = (u16*)alloc(1048576ull * 2);    // w_out bf16            (2 MiB)
    u16* xpb   = (u16*)alloc(16777216ull * 2);   // x_proj bf16           (32 MiB)
    u16* qkvb  = (u16*)alloc(50331648ull * 2);   // qf/kf/v bf16          (96 MiB)
    float* kvp = (float*)alloc(512ull * 4096 * 4);  // kv partials        (8 MiB)
    float* ksp = (float*)alloc(512ull * 64 * 4);    // ksum partials
    float* kvr = (float*)alloc(64ull * 4096 * 4);   // kv reduced         (1 MiB)
    float* ksr = (float*)alloc(64ull * 64 * 4);     // ksum reduced
    u16* attnb = (u16*)alloc(16777216ull * 2);   // attn out bf16 == GEMM3 A (32 MiB)

    cvt_kernel<<<2048, 256, 0, stream>>>(x, xb, 8388608 / 4);
    cvt_kernel<<<512, 256, 0, stream>>>(w_in, wib, 524288 / 4);
    cvt_kernel<<<1024, 256, 0, stream>>>(w_qkv, wqb, 3145728 / 4);
    cvt_kernel<<<1024, 256, 0, stream>>>(w_out, wob, 1048576 / 4);

    // GEMM1: x(16384x512) @ w_in^T -> x_proj bf16 (16384x1024)
    gemm_bt<0><<<1024, 256, 0, stream>>>(xb, wib, nullptr, xpb, nullptr, 1024, 512);
    // GEMM2: x_proj(16384x1024) @ w_qkv^T -> qkv (16384x3072), elu+1 on q,k
    gemm_bt<1><<<3072, 256, 0, stream>>>(xpb, wqb, nullptr, qkvb, nullptr, 3072, 1024);

    attn_kv<<<512, 256, 0, stream>>>(qkvb, kvp, ksp);
    attn_red<<<64, 256, 0, stream>>>(kvp, ksp, kvr, ksr);
    attn_out<<<4096, 256, 0, stream>>>(qkvb, kvr, ksr, attnb);

    // GEMM3: attn(16384x1024) @ w_out^T + x_proj -> out (f32)
    gemm_bt<2><<<1024, 256, 0, stream>>>(attnb, wob, out, nullptr, xpb, 1024, 1024);
    rms_kernel<<<16384, 256, 0, stream>>>(out, normw);
}

// Round 4
// 435.034 us; speedup vs baseline: 1.1119x; 1.1119x over previous
//
#include <hip/hip_runtime.h>
#include <stdint.h>

typedef unsigned short u16;
typedef unsigned int u32;

typedef __bf16 bf16_t;
typedef bf16_t bf16x8 __attribute__((ext_vector_type(8)));
typedef float f32x4 __attribute__((ext_vector_type(4)));

__device__ __forceinline__ u16 f2b(float f) {
    u32 u = __builtin_bit_cast(u32, f);
    u += 0x7FFFu + ((u >> 16) & 1u);   // RNE
    return (u16)(u >> 16);
}
__device__ __forceinline__ float b2f(u16 h) {
    return __builtin_bit_cast(float, (u32)h << 16);
}

__device__ __forceinline__ void gld_lds16(const void* gptr, void* lptr) {
    __builtin_amdgcn_global_load_lds(
        (const __attribute__((address_space(1))) void*)gptr,
        (__attribute__((address_space(3))) void*)lptr,
        16, 0, 0);
}

// ---------------- f32 -> bf16 conversion ----------------
__global__ __launch_bounds__(256) void cvt_kernel(const float* __restrict__ s,
                                                  u16* __restrict__ d, int n4) {
    int i = blockIdx.x * 256 + threadIdx.x;
    const int stride = gridDim.x * 256;
    for (; i < n4; i += stride) {
        float4 v = reinterpret_cast<const float4*>(s)[i];
        uint2 o;
        o.x = (u32)f2b(v.x) | ((u32)f2b(v.y) << 16);
        o.y = (u32)f2b(v.z) | ((u32)f2b(v.w) << 16);
        reinterpret_cast<uint2*>(d)[i] = o;
    }
}

// ---------------- BT GEMM: C[M,N] = A[M,K] * B[N,K]^T, bf16 in, f32 acc ----
// 128x128 tile, BK=64, 4 waves (2x2 of 64x64), 16x16x32 MFMA.
// EPI 0: store bf16                           (GEMM1: x_proj)
// EPI 1: elu+1 for cols<2048, store bf16      (GEMM2: qkv)
// EPI 2: add bf16 resid, store f32            (GEMM3: out proj + residual)
template <int EPI>
__global__ __launch_bounds__(256) void gemm_bt(
    const u16* __restrict__ A, const u16* __restrict__ Bw,
    float* __restrict__ outF, u16* __restrict__ outB,
    const u16* __restrict__ residB, int N, int K)
{
    __shared__ u16 As[8192];   // [128][64] bf16, 128 B per row
    __shared__ u16 Bs[8192];

    const int t = threadIdx.x;
    const int ntile = N >> 7;
    const int mt = blockIdx.x / ntile;
    const int nt = blockIdx.x - mt * ntile;
    const size_t brow = (size_t)mt << 7;
    const size_t bcol = (size_t)nt << 7;

    const int lane = t & 63;
    const int wv = t >> 6;
    const int wrow = (wv >> 1) << 6;
    const int wcol = (wv & 1) << 6;
    const int fr = lane & 15;
    const int fk = lane >> 4;
    const int swz = (fr & 7) << 4;

    f32x4 acc[4][4] = {};

    const int srow = t >> 3;
    const int pb = (t & 7) << 4;

    for (int k0 = 0; k0 < K; k0 += 64) {
#pragma unroll
        for (int i = 0; i < 4; ++i) {
            const int row = (i << 5) + srow;
            const int kb = pb ^ ((row & 7) << 4);   // inverse-swizzled global source
            const u16* ga = A + (brow + row) * (size_t)K + (k0 + (kb >> 1));
            const u16* gb = Bw + (bcol + row) * (size_t)K + (k0 + (kb >> 1));
            gld_lds16(ga, As + (i << 11) + t * 8);  // linear LDS dest
            gld_lds16(gb, Bs + (i << 11) + t * 8);
        }
        __syncthreads();
#pragma unroll
        for (int ks = 0; ks < 2; ++ks) {
            const int col = ((ks << 6) | (fk << 4)) ^ swz;  // swizzled read (bytes)
            bf16x8 af[4], bfr[4];
#pragma unroll
            for (int i = 0; i < 4; ++i) {
                af[i]  = *(const bf16x8*)((const char*)As + (wrow + (i << 4) + fr) * 128 + col);
                bfr[i] = *(const bf16x8*)((const char*)Bs + (wcol + (i << 4) + fr) * 128 + col);
            }
#pragma unroll
            for (int i = 0; i < 4; ++i)
#pragma unroll
                for (int j = 0; j < 4; ++j)
                    acc[i][j] = __builtin_amdgcn_mfma_f32_16x16x32_bf16(
                        af[i], bfr[j], acc[i][j], 0, 0, 0);
        }
        __syncthreads();
    }

    // C/D mapping: col = lane&15, row = (lane>>4)*4 + reg
    const int r0 = (lane >> 4) << 2;
    const int c0 = lane & 15;
#pragma unroll
    for (int i = 0; i < 4; ++i) {
#pragma unroll
        for (int r = 0; r < 4; ++r) {
            const size_t grow = brow + wrow + (i << 4) + r0 + r;
#pragma unroll
            for (int j = 0; j < 4; ++j) {
                const size_t gcol = bcol + wcol + (j << 4) + c0;
                float v = acc[i][j][r];
                const size_t idx = grow * (size_t)N + gcol;
                if (EPI == 0) {
                    outB[idx] = f2b(v);
                } else if (EPI == 1) {
                    if (gcol < 2048) v = (v > 0.f) ? (v + 1.f) : __expf(v);  // elu+1
                    outB[idx] = f2b(v);
                } else {
                    outF[idx] = v + b2f(residB[idx]);
                }
            }
        }
    }
}

// ---------------- linear attention: partial kv (64x64) + ksum over L-split ----
// grid: bh(64) * split(8); qkv layout: [b][l][s(3)][h(16)][d(64)] bf16
// Register-blocked: thread (dg = t>>5, mp = t&31) owns acc[8 d][2 m];
// per l-iter: 1x ds_read_b128 (kf 8d) + 1x ds_read_b32 (v pair).
__global__ __launch_bounds__(256) void attn_kv(
    const u16* __restrict__ qkvb, float* __restrict__ kvpart, float* __restrict__ kspart)
{
    __shared__ __align__(16) u16 kfs[2048];  // [32 l][64 d]
    __shared__ __align__(16) u16 vss[2048];
    __shared__ float ksp[4][64];
    const int t = threadIdx.x;
    const int bh = blockIdx.x >> 3;
    const int split = blockIdx.x & 7;
    const int b = bh >> 4, h = bh & 15;
    const size_t base = (size_t)b * (4096 * 3072) + h * 64;
    const int wv = t >> 6, lane = t & 63;
    const int lload = t >> 3, dload = (t & 7) << 3;
    const int dg = t >> 5;          // 0..7 -> d0 = dg*8
    const int m0 = (t & 31) << 1;   // 0..62 even

    float acc[8][2] = {};
    float ks = 0.f;

    for (int c = 0; c < 512; c += 32) {
        __syncthreads();
        const size_t l = (size_t)split * 512 + c + lload;
        *(uint4*)(kfs + lload * 64 + dload) = *(const uint4*)(qkvb + base + l * 3072 + 1024 + dload);
        *(uint4*)(vss + lload * 64 + dload) = *(const uint4*)(qkvb + base + l * 3072 + 2048 + dload);
        __syncthreads();
#pragma unroll 4
        for (int ll = 0; ll < 32; ++ll) {
            const uint4 kfu = *(const uint4*)(kfs + ll * 64 + (dg << 3));
            const u32 vu = *(const u32*)(vss + ll * 64 + m0);
            const float v0 = __builtin_bit_cast(float, vu << 16);
            const float v1 = __builtin_bit_cast(float, vu & 0xFFFF0000u);
            const u32 kw[4] = {kfu.x, kfu.y, kfu.z, kfu.w};
#pragma unroll
            for (int p = 0; p < 4; ++p) {
                const float klo = __builtin_bit_cast(float, kw[p] << 16);
                const float khi = __builtin_bit_cast(float, kw[p] & 0xFFFF0000u);
                acc[2 * p][0]     += klo * v0;
                acc[2 * p][1]     += klo * v1;
                acc[2 * p + 1][0] += khi * v0;
                acc[2 * p + 1][1] += khi * v1;
            }
        }
        const int lb = wv << 3;
#pragma unroll
        for (int q = 0; q < 8; ++q) ks += b2f(kfs[(lb + q) * 64 + lane]);
    }
    ksp[wv][lane] = ks;
    const size_t obase = (size_t)blockIdx.x * 4096;
#pragma unroll
    for (int i = 0; i < 8; ++i) {
        float2 w = {acc[i][0], acc[i][1]};
        *(float2*)(kvpart + obase + (size_t)((dg << 3) + i) * 64 + m0) = w;
    }
    __syncthreads();
    if (t < 64)
        kspart[(size_t)blockIdx.x * 64 + t] = ksp[0][t] + ksp[1][t] + ksp[2][t] + ksp[3][t];
}

// ---------------- reduce 8 partials -> bf16 B-tile for attn_out ----------------
// kvtb per bh: [96 rows][64 d] bf16: rows 0..63 = kvT[m][d], row 64 = ksum[d],
// rows 65..95 = 0.
__global__ __launch_bounds__(256) void attn_red(
    const float* __restrict__ kvpart, const float* __restrict__ kspart,
    u16* __restrict__ kvtb)
{
    const int bh = blockIdx.x;
    const int t = threadIdx.x;
    const size_t pbase = (size_t)bh * 8 * 4096;
    u16* ob = kvtb + (size_t)bh * 6144;
#pragma unroll 2
    for (int rep = 0; rep < 16; ++rep) {
        const int e = rep * 256 + t;   // e = d*64 + m
        float s = 0.f;
#pragma unroll
        for (int p = 0; p < 8; ++p) s += kvpart[pbase + (size_t)p * 4096 + e];
        const int d = e >> 6, m = e & 63;
        ob[m * 64 + d] = f2b(s);       // transposed
    }
    if (t < 64) {
        float s = 0.f;
#pragma unroll
        for (int p = 0; p < 8; ++p) s += kspart[(size_t)(bh * 8 + p) * 64 + t];
        ob[64 * 64 + t] = f2b(s);
    }
    for (int z = t; z < 1984; z += 256) ob[65 * 64 + z] = 0;
}

// ---------------- attn_out via MFMA ----------------
// out[l][m] = (qf[l,:] . kvT[m,:]) / (qf[l,:] . ksum + 1e-8)
// A = qf rows (natural [l][64] layout in qkvb), B = kvtb (96x64), K = 64.
// Block: 128 l-rows x 96 cols, 4 waves x 32 l-rows each, acc[2][5] (col frag 4 = nrm).
__global__ __launch_bounds__(256) void attn_out_mfma(
    const u16* __restrict__ qkvb, const u16* __restrict__ kvtb,
    u16* __restrict__ attnb)
{
    __shared__ u16 As[8192];   // [128 l][64 d]
    __shared__ u16 Bs[6144];   // [96 m'][64 d]
    const int t = threadIdx.x;
    const int bh = blockIdx.x >> 5;
    const int lt = blockIdx.x & 31;
    const int b = bh >> 4, h = bh & 15;
    const size_t qbase = (size_t)b * (4096 * 3072) + h * 64;
    const int l0 = lt << 7;

    const int lane = t & 63;
    const int wv = t >> 6;
    const int fr = lane & 15;
    const int fk = lane >> 4;
    const int swz = (fr & 7) << 4;
    const int srow = t >> 3;
    const int pb = (t & 7) << 4;

#pragma unroll
    for (int i = 0; i < 4; ++i) {
        const int row = (i << 5) + srow;
        const int kb = pb ^ ((row & 7) << 4);
        gld_lds16(qkvb + qbase + (size_t)(l0 + row) * 3072 + (kb >> 1),
                  As + (i << 11) + t * 8);
    }
#pragma unroll
    for (int i = 0; i < 3; ++i) {
        const int row = (i << 5) + srow;
        const int kb = pb ^ ((row & 7) << 4);
        gld_lds16(kvtb + (size_t)bh * 6144 + row * 64 + (kb >> 1),
                  Bs + (i << 11) + t * 8);
    }
    __syncthreads();

    f32x4 acc[2][5] = {};
    const int wrow = wv << 5;
#pragma unroll
    for (int ks = 0; ks < 2; ++ks) {
        const int col = ((ks << 6) | (fk << 4)) ^ swz;
        bf16x8 af[2], bfr[5];
#pragma unroll
        for (int i = 0; i < 2; ++i)
            af[i] = *(const bf16x8*)((const char*)As + (wrow + (i << 4) + fr) * 128 + col);
#pragma unroll
        for (int j = 0; j < 5; ++j)
            bfr[j] = *(const bf16x8*)((const char*)Bs + ((j << 4) + fr) * 128 + col);
#pragma unroll
        for (int i = 0; i < 2; ++i)
#pragma unroll
            for (int j = 0; j < 5; ++j)
                acc[i][j] = __builtin_amdgcn_mfma_f32_16x16x32_bf16(
                    af[i], bfr[j], acc[i][j], 0, 0, 0);
    }

    const int r0 = (lane >> 4) << 2;
    const int c0 = lane & 15;
#pragma unroll
    for (int i = 0; i < 2; ++i) {
#pragma unroll
        for (int r = 0; r < 4; ++r) {
            const int row = wrow + (i << 4) + r0 + r;
            const float nv = __shfl(acc[i][4][r], lane & 48, 64);  // col 64 = nrm
            const float inv = 1.f / (nv + 1e-8f);
            const size_t obase = ((size_t)bh * 4096 + l0 + row) * 64;
#pragma unroll
            for (int j = 0; j < 4; ++j)
                attnb[obase + (j << 4) + c0] = f2b(acc[i][j][r] * inv);
        }
    }
}

// ---------------- RMS norm (in-place), one block per row of 1024 ----------------
__global__ __launch_bounds__(256) void rms_kernel(float* __restrict__ y,
                                                  const float* __restrict__ nw)
{
    __shared__ float red[4];
    const size_t row = blockIdx.x;
    const int t = threadIdx.x;
    float4 v = *(float4*)(y + row * 1024 + t * 4);
    float s = v.x * v.x + v.y * v.y + v.z * v.z + v.w * v.w;
#pragma unroll
    for (int off = 32; off > 0; off >>= 1) s += __shfl_down(s, off, 64);
    if ((t & 63) == 0) red[t >> 6] = s;
    __syncthreads();
    const float tot = red[0] + red[1] + red[2] + red[3];
    const float rms = rsqrtf(tot * (1.f / 1024.f) + 1.1920929e-7f);
    const float4 w = *(const float4*)(nw + t * 4);
    v.x *= rms * w.x; v.y *= rms * w.y; v.z *= rms * w.z; v.w *= rms * w.w;
    *(float4*)(y + row * 1024 + t * 4) = v;
}

extern "C" void kernel_launch(void* const* d_in, const int* in_sizes, int n_in,
                              void* d_out, int out_size, void* d_ws, size_t ws_size,
                              hipStream_t stream)
{
    const float* x     = (const float*)d_in[0];   // (4,4096,512)
    const float* w_in  = (const float*)d_in[1];   // (1024,512)
    const float* w_qkv = (const float*)d_in[2];   // (3072,1024)
    const float* w_out = (const float*)d_in[3];   // (1024,1024)
    const float* normw = (const float*)d_in[4];   // (1024,)
    float* out = (float*)d_out;                   // (4,4096,1024) f32

    char* ws = (char*)d_ws;
    size_t off = 0;
    auto alloc = [&](size_t bytes) {
        char* p = ws + off;
        off += (bytes + 255) & ~(size_t)255;
        return p;
    };
    // total ws usage ~193 MiB
    u16* xb    = (u16*)alloc(8388608ull * 2);    // x bf16                (16 MiB)
    u16* wib   = (u16*)alloc(524288ull * 2);     // w_in bf16             (1 MiB)
    u16* wqb   = (u16*)alloc(3145728ull * 2);    // w_qkv bf16            (6 MiB)
    u16* wob   = (u16*)alloc(1048576ull * 2);    // w_out bf16            (2 MiB)
    u16* xpb   = (u16*)alloc(16777216ull * 2);   // x_proj bf16           (32 MiB)
    u16* qkvb  = (u16*)alloc(50331648ull * 2);   // qf/kf/v bf16          (96 MiB)
    float* kvp = (float*)alloc(512ull * 4096 * 4);  // kv partials        (8 MiB)
    float* ksp = (float*)alloc(512ull * 64 * 4);    // ksum partials
    u16* kvtb  = (u16*)alloc(64ull * 96 * 64 * 2);  // kvT+ksum bf16 tile (768 KiB)
    u16* attnb = (u16*)alloc(16777216ull * 2);   // attn out bf16 == GEMM3 A (32 MiB)

    cvt_kernel<<<2048, 256, 0, stream>>>(x, xb, 8388608 / 4);
    cvt_kernel<<<512, 256, 0, stream>>>(w_in, wib, 524288 / 4);
    cvt_kernel<<<1024, 256, 0, stream>>>(w_qkv, wqb, 3145728 / 4);
    cvt_kernel<<<1024, 256, 0, stream>>>(w_out, wob, 1048576 / 4);

    // GEMM1: x(16384x512) @ w_in^T -> x_proj bf16 (16384x1024)
    gemm_bt<0><<<1024, 256, 0, stream>>>(xb, wib, nullptr, xpb, nullptr, 1024, 512);
    // GEMM2: x_proj(16384x1024) @ w_qkv^T -> qkv (16384x3072), elu+1 on q,k
    gemm_bt<1><<<3072, 256, 0, stream>>>(xpb, wqb, nullptr, qkvb, nullptr, 3072, 1024);

    attn_kv<<<512, 256, 0, stream>>>(qkvb, kvp, ksp);
    attn_red<<<64, 256, 0, stream>>>(kvp, ksp, kvtb);
    attn_out_mfma<<<2048, 256, 0, stream>>>(qkvb, kvtb, attnb);

    // GEMM3: attn(16384x1024) @ w_out^T + x_proj -> out (f32)
    gemm_bt<2><<<1024, 256, 0, stream>>>(attnb, wob, out, nullptr, xpb, 1024, 1024);
    rms_kernel<<<16384, 256, 0, stream>>>(out, normw);
}

// Round 5
// 389.130 us; speedup vs baseline: 1.2431x; 1.1180x over previous
//
#include <hip/hip_runtime.h>
#include <stdint.h>

typedef unsigned short u16;
typedef unsigned int u32;

typedef __bf16 bf16_t;
typedef bf16_t bf16x8 __attribute__((ext_vector_type(8)));
typedef float f32x4 __attribute__((ext_vector_type(4)));

__device__ __forceinline__ u16 f2b(float f) {
    u32 u = __builtin_bit_cast(u32, f);
    u += 0x7FFFu + ((u >> 16) & 1u);   // RNE
    return (u16)(u >> 16);
}
__device__ __forceinline__ float b2f(u16 h) {
    return __builtin_bit_cast(float, (u32)h << 16);
}

__device__ __forceinline__ void gld_lds16(const void* gptr, void* lptr) {
    __builtin_amdgcn_global_load_lds(
        (const __attribute__((address_space(1))) void*)gptr,
        (__attribute__((address_space(3))) void*)lptr,
        16, 0, 0);
}

// ---------------- f32 -> bf16 conversion ----------------
__global__ __launch_bounds__(256) void cvt_kernel(const float* __restrict__ s,
                                                  u16* __restrict__ d, int n4) {
    int i = blockIdx.x * 256 + threadIdx.x;
    const int stride = gridDim.x * 256;
    for (; i < n4; i += stride) {
        float4 v = reinterpret_cast<const float4*>(s)[i];
        uint2 o;
        o.x = (u32)f2b(v.x) | ((u32)f2b(v.y) << 16);
        o.y = (u32)f2b(v.z) | ((u32)f2b(v.w) << 16);
        reinterpret_cast<uint2*>(d)[i] = o;
    }
}

// ======== 256x256 8-phase BT GEMM: C[M,N] = A[M,K]*B[N,K]^T, bf16, f32 acc ===
// 512 thr = 8 waves (2M x 4N); per-wave 128x64 out = 8 Mfrag x 4 Nfrag 16x16.
// LDS 128 KiB: AS[2][256][64] + BS[2][256][64] bf16; K-tile kt -> buf kt&1.
// 8 phases per 2 K-tiles; quadrant order (qm,qn)=(00,01,11,10); stage rotation
// fills just-freed halves; vmcnt(4) gates only at phases 4 and 8.
// Swizzle: inverse-swizzled global source + XOR on ds_read (byte^=(row&7)<<4).
#define PHASE(c, qm, qn, STAGES, GATE) do {                                    \
    bf16x8 af[4][2]; bf16x8 bfv[2][2];                                         \
    _Pragma("unroll") for (int ii = 0; ii < 4; ++ii) {                         \
        const int r = (qm)*128 + wm*64 + ii*16 + fr;                           \
        const char* pa = (const char*)AS[c] + r*128; const int rs = (r&7)<<4;  \
        af[ii][0] = *(const bf16x8*)(pa + ((fk<<4)^rs));                       \
        af[ii][1] = *(const bf16x8*)(pa + ((64|(fk<<4))^rs)); }                \
    _Pragma("unroll") for (int jj = 0; jj < 2; ++jj) {                         \
        const int r = (qn)*128 + wn*32 + jj*16 + fr;                           \
        const char* pb = (const char*)BS[c] + r*128; const int rs = (r&7)<<4;  \
        bfv[jj][0] = *(const bf16x8*)(pb + ((fk<<4)^rs));                      \
        bfv[jj][1] = *(const bf16x8*)(pb + ((64|(fk<<4))^rs)); }               \
    STAGES;                                                                    \
    __builtin_amdgcn_s_barrier();                                              \
    __builtin_amdgcn_s_setprio(1);                                             \
    _Pragma("unroll") for (int ks = 0; ks < 2; ++ks)                           \
      _Pragma("unroll") for (int ii = 0; ii < 4; ++ii)                         \
        _Pragma("unroll") for (int jj = 0; jj < 2; ++jj)                       \
            acc[(qm)*4+ii][(qn)*2+jj] = __builtin_amdgcn_mfma_f32_16x16x32_bf16( \
                af[ii][ks], bfv[jj][ks], acc[(qm)*4+ii][(qn)*2+jj], 0, 0, 0);  \
    __builtin_amdgcn_s_setprio(0);                                             \
    GATE;                                                                      \
    __builtin_amdgcn_s_barrier();                                              \
} while (0)

#define VGATE asm volatile("s_waitcnt vmcnt(4)" ::: "memory")
#define NOGATE ((void)0)

template <int EPI>
__global__ __launch_bounds__(512) void gemm_bt256(
    const u16* __restrict__ A, const u16* __restrict__ Bw,
    float* __restrict__ outF, u16* __restrict__ outB,
    const u16* __restrict__ residB, int N, int K)
{
    __shared__ u16 AS[2][16384];   // [buf][256 rows][64 k]
    __shared__ u16 BS[2][16384];

    const int t = threadIdx.x;
    const int ntile = N >> 8;
    const int nwg = gridDim.x;
    const int wg = ((int)blockIdx.x & 7) * (nwg >> 3) + ((int)blockIdx.x >> 3);
    const int mt = wg / ntile;
    const int nt = wg - mt * ntile;
    const size_t brow = (size_t)mt << 8;
    const size_t bcol = (size_t)nt << 8;

    const int lane = t & 63, wv = t >> 6;
    const int wm = wv >> 2, wn = wv & 3;
    const int fr = lane & 15, fk = lane >> 4;
    const int nkt = K >> 6;
    const int niter = nkt >> 1;

    f32x4 acc[8][4] = {};

    // stage one half-tile (128 rows x 64 k = 16 KiB) of A or B into buf c
    auto STG = [&](int c, int half, int isA, int kt) {
        const u16* G = isA ? A : Bw;
        const size_t g0 = isA ? brow : bcol;
        u16* lds = isA ? AS[c] : BS[c];
        const int k0 = kt << 6;
#pragma unroll
        for (int j = 0; j < 2; ++j) {
            const int row = (half << 7) + (j << 6) + (t >> 3);
            const int kb = ((t & 7) << 4) ^ ((row & 7) << 4);  // inv-swizzled src
            gld_lds16(G + (g0 + row) * (size_t)K + k0 + (kb >> 1),
                      lds + row * 64 + (t & 7) * 8);           // linear dest
        }
    };

    // prologue: kt0 all 4 halves; kt1 Ah0+Bh1 (its Ah1/Bh0 come at ph1/ph2)
    STG(0, 0, 1, 0); STG(0, 1, 1, 0); STG(0, 0, 0, 0); STG(0, 1, 0, 0);
    STG(1, 0, 1, 1); STG(1, 1, 0, 1);
    asm volatile("s_waitcnt vmcnt(4)" ::: "memory");   // kt0 landed; kt1 pair in flight
    __builtin_amdgcn_s_barrier();

#pragma unroll 1
    for (int i = 0; i < niter; ++i) {
        const int kt1 = 2 * i + 1, kt2 = 2 * i + 2, kt3 = 2 * i + 3;
        const bool more = kt2 < nkt;
        PHASE(0, 0, 0, STG(1, 1, 1, kt1), NOGATE);                  // ph1
        PHASE(0, 0, 1, STG(1, 0, 0, kt1), NOGATE);                  // ph2
        PHASE(0, 1, 1, if (more) STG(0, 0, 1, kt2), NOGATE);        // ph3
        PHASE(0, 1, 0, if (more) STG(0, 1, 0, kt2), VGATE);         // ph4
        PHASE(1, 0, 0, if (more) STG(0, 1, 1, kt2), NOGATE);        // ph5
        PHASE(1, 0, 1, if (more) STG(0, 0, 0, kt2), NOGATE);        // ph6
        PHASE(1, 1, 1, if (more) STG(1, 0, 1, kt3), NOGATE);        // ph7
        PHASE(1, 1, 0, if (more) STG(1, 1, 0, kt3), VGATE);         // ph8
    }

    // C/D mapping: col = lane&15, row = (lane>>4)*4 + reg
    const int r0 = (lane >> 4) << 2;
    const int c0 = lane & 15;
#pragma unroll
    for (int f = 0; f < 8; ++f) {
        const size_t growb = brow + ((f >> 2) * 128 + wm * 64 + (f & 3) * 16 + r0);
#pragma unroll
        for (int r = 0; r < 4; ++r) {
            const size_t grow = growb + r;
#pragma unroll
            for (int g = 0; g < 4; ++g) {
                const size_t gcol = bcol + ((g >> 1) * 128 + wn * 32 + (g & 1) * 16) + c0;
                float v = acc[f][g][r];
                const size_t idx = grow * (size_t)N + gcol;
                if (EPI == 0) {
                    outB[idx] = f2b(v);
                } else if (EPI == 1) {
                    if (gcol < 2048) v = (v > 0.f) ? (v + 1.f) : __expf(v);  // elu+1
                    outB[idx] = f2b(v);
                } else {
                    outF[idx] = v + b2f(residB[idx]);
                }
            }
        }
    }
}

// ---------------- linear attention: partial kv (64x64) + ksum over L-split ----
__global__ __launch_bounds__(256) void attn_kv(
    const u16* __restrict__ qkvb, float* __restrict__ kvpart, float* __restrict__ kspart)
{
    __shared__ __align__(16) u16 kfs[2048];  // [32 l][64 d]
    __shared__ __align__(16) u16 vss[2048];
    __shared__ float ksp[4][64];
    const int t = threadIdx.x;
    const int bh = blockIdx.x >> 3;
    const int split = blockIdx.x & 7;
    const int b = bh >> 4, h = bh & 15;
    const size_t base = (size_t)b * (4096 * 3072) + h * 64;
    const int wv = t >> 6, lane = t & 63;
    const int lload = t >> 3, dload = (t & 7) << 3;
    const int dg = t >> 5;
    const int m0 = (t & 31) << 1;

    float acc[8][2] = {};
    float ks = 0.f;

    for (int c = 0; c < 512; c += 32) {
        __syncthreads();
        const size_t l = (size_t)split * 512 + c + lload;
        *(uint4*)(kfs + lload * 64 + dload) = *(const uint4*)(qkvb + base + l * 3072 + 1024 + dload);
        *(uint4*)(vss + lload * 64 + dload) = *(const uint4*)(qkvb + base + l * 3072 + 2048 + dload);
        __syncthreads();
#pragma unroll 4
        for (int ll = 0; ll < 32; ++ll) {
            const uint4 kfu = *(const uint4*)(kfs + ll * 64 + (dg << 3));
            const u32 vu = *(const u32*)(vss + ll * 64 + m0);
            const float v0 = __builtin_bit_cast(float, vu << 16);
            const float v1 = __builtin_bit_cast(float, vu & 0xFFFF0000u);
            const u32 kw[4] = {kfu.x, kfu.y, kfu.z, kfu.w};
#pragma unroll
            for (int p = 0; p < 4; ++p) {
                const float klo = __builtin_bit_cast(float, kw[p] << 16);
                const float khi = __builtin_bit_cast(float, kw[p] & 0xFFFF0000u);
                acc[2 * p][0]     += klo * v0;
                acc[2 * p][1]     += klo * v1;
                acc[2 * p + 1][0] += khi * v0;
                acc[2 * p + 1][1] += khi * v1;
            }
        }
        const int lb = wv << 3;
#pragma unroll
        for (int q = 0; q < 8; ++q) ks += b2f(kfs[(lb + q) * 64 + lane]);
    }
    ksp[wv][lane] = ks;
    const size_t obase = (size_t)blockIdx.x * 4096;
#pragma unroll
    for (int i = 0; i < 8; ++i) {
        float2 w = {acc[i][0], acc[i][1]};
        *(float2*)(kvpart + obase + (size_t)((dg << 3) + i) * 64 + m0) = w;
    }
    __syncthreads();
    if (t < 64)
        kspart[(size_t)blockIdx.x * 64 + t] = ksp[0][t] + ksp[1][t] + ksp[2][t] + ksp[3][t];
}

// ---------------- reduce 8 partials -> bf16 B-tile for attn_out ----------------
__global__ __launch_bounds__(256) void attn_red(
    const float* __restrict__ kvpart, const float* __restrict__ kspart,
    u16* __restrict__ kvtb)
{
    const int bh = blockIdx.x;
    const int t = threadIdx.x;
    const size_t pbase = (size_t)bh * 8 * 4096;
    u16* ob = kvtb + (size_t)bh * 6144;
#pragma unroll 2
    for (int rep = 0; rep < 16; ++rep) {
        const int e = rep * 256 + t;   // e = d*64 + m
        float s = 0.f;
#pragma unroll
        for (int p = 0; p < 8; ++p) s += kvpart[pbase + (size_t)p * 4096 + e];
        const int d = e >> 6, m = e & 63;
        ob[m * 64 + d] = f2b(s);       // transposed
    }
    if (t < 64) {
        float s = 0.f;
#pragma unroll
        for (int p = 0; p < 8; ++p) s += kspart[(size_t)(bh * 8 + p) * 64 + t];
        ob[64 * 64 + t] = f2b(s);
    }
    for (int z = t; z < 1984; z += 256) ob[65 * 64 + z] = 0;
}

// ---------------- attn_out via MFMA ----------------
__global__ __launch_bounds__(256) void attn_out_mfma(
    const u16* __restrict__ qkvb, const u16* __restrict__ kvtb,
    u16* __restrict__ attnb)
{
    __shared__ u16 As[8192];   // [128 l][64 d]
    __shared__ u16 Bs[6144];   // [96 m'][64 d]
    const int t = threadIdx.x;
    const int bh = blockIdx.x >> 5;
    const int lt = blockIdx.x & 31;
    const int b = bh >> 4, h = bh & 15;
    const size_t qbase = (size_t)b * (4096 * 3072) + h * 64;
    const int l0 = lt << 7;

    const int lane = t & 63;
    const int wv = t >> 6;
    const int fr = lane & 15;
    const int fk = lane >> 4;
    const int swz = (fr & 7) << 4;
    const int srow = t >> 3;
    const int pb = (t & 7) << 4;

#pragma unroll
    for (int i = 0; i < 4; ++i) {
        const int row = (i << 5) + srow;
        const int kb = pb ^ ((row & 7) << 4);
        gld_lds16(qkvb + qbase + (size_t)(l0 + row) * 3072 + (kb >> 1),
                  As + (i << 11) + t * 8);
    }
#pragma unroll
    for (int i = 0; i < 3; ++i) {
        const int row = (i << 5) + srow;
        const int kb = pb ^ ((row & 7) << 4);
        gld_lds16(kvtb + (size_t)bh * 6144 + row * 64 + (kb >> 1),
                  Bs + (i << 11) + t * 8);
    }
    __syncthreads();

    f32x4 acc[2][5] = {};
    const int wrow = wv << 5;
#pragma unroll
    for (int ks = 0; ks < 2; ++ks) {
        const int col = ((ks << 6) | (fk << 4)) ^ swz;
        bf16x8 af[2], bfr[5];
#pragma unroll
        for (int i = 0; i < 2; ++i)
            af[i] = *(const bf16x8*)((const char*)As + (wrow + (i << 4) + fr) * 128 + col);
#pragma unroll
        for (int j = 0; j < 5; ++j)
            bfr[j] = *(const bf16x8*)((const char*)Bs + ((j << 4) + fr) * 128 + col);
#pragma unroll
        for (int i = 0; i < 2; ++i)
#pragma unroll
            for (int j = 0; j < 5; ++j)
                acc[i][j] = __builtin_amdgcn_mfma_f32_16x16x32_bf16(
                    af[i], bfr[j], acc[i][j], 0, 0, 0);
    }

    const int r0 = (lane >> 4) << 2;
    const int c0 = lane & 15;
#pragma unroll
    for (int i = 0; i < 2; ++i) {
#pragma unroll
        for (int r = 0; r < 4; ++r) {
            const int row = wrow + (i << 4) + r0 + r;
            const float nv = __shfl(acc[i][4][r], lane & 48, 64);  // col 64 = nrm
            const float inv = 1.f / (nv + 1e-8f);
            const size_t obase = ((size_t)bh * 4096 + l0 + row) * 64;
#pragma unroll
            for (int j = 0; j < 4; ++j)
                attnb[obase + (j << 4) + c0] = f2b(acc[i][j][r] * inv);
        }
    }
}

// ---------------- RMS norm (in-place), one block per row of 1024 ----------------
__global__ __launch_bounds__(256) void rms_kernel(float* __restrict__ y,
                                                  const float* __restrict__ nw)
{
    __shared__ float red[4];
    const size_t row = blockIdx.x;
    const int t = threadIdx.x;
    float4 v = *(float4*)(y + row * 1024 + t * 4);
    float s = v.x * v.x + v.y * v.y + v.z * v.z + v.w * v.w;
#pragma unroll
    for (int off = 32; off > 0; off >>= 1) s += __shfl_down(s, off, 64);
    if ((t & 63) == 0) red[t >> 6] = s;
    __syncthreads();
    const float tot = red[0] + red[1] + red[2] + red[3];
    const float rms = rsqrtf(tot * (1.f / 1024.f) + 1.1920929e-7f);
    const float4 w = *(const float4*)(nw + t * 4);
    v.x *= rms * w.x; v.y *= rms * w.y; v.z *= rms * w.z; v.w *= rms * w.w;
    *(float4*)(y + row * 1024 + t * 4) = v;
}

extern "C" void kernel_launch(void* const* d_in, const int* in_sizes, int n_in,
                              void* d_out, int out_size, void* d_ws, size_t ws_size,
                              hipStream_t stream)
{
    const float* x     = (const float*)d_in[0];   // (4,4096,512)
    const float* w_in  = (const float*)d_in[1];   // (1024,512)
    const float* w_qkv = (const float*)d_in[2];   // (3072,1024)
    const float* w_out = (const float*)d_in[3];   // (1024,1024)
    const float* normw = (const float*)d_in[4];   // (1024,)
    float* out = (float*)d_out;                   // (4,4096,1024) f32

    char* ws = (char*)d_ws;
    size_t off = 0;
    auto alloc = [&](size_t bytes) {
        char* p = ws + off;
        off += (bytes + 255) & ~(size_t)255;
        return p;
    };
    // total ws usage ~193 MiB
    u16* xb    = (u16*)alloc(8388608ull * 2);    // x bf16                (16 MiB)
    u16* wib   = (u16*)alloc(524288ull * 2);     // w_in bf16             (1 MiB)
    u16* wqb   = (u16*)alloc(3145728ull * 2);    // w_qkv bf16            (6 MiB)
    u16* wob   = (u16*)alloc(1048576ull * 2);    // w_out bf16            (2 MiB)
    u16* xpb   = (u16*)alloc(16777216ull * 2);   // x_proj bf16           (32 MiB)
    u16* qkvb  = (u16*)alloc(50331648ull * 2);   // qf/kf/v bf16          (96 MiB)
    float* kvp = (float*)alloc(512ull * 4096 * 4);  // kv partials        (8 MiB)
    float* ksp = (float*)alloc(512ull * 64 * 4);    // ksum partials
    u16* kvtb  = (u16*)alloc(64ull * 96 * 64 * 2);  // kvT+ksum bf16 tile (768 KiB)
    u16* attnb = (u16*)alloc(16777216ull * 2);   // attn out bf16 == GEMM3 A (32 MiB)

    cvt_kernel<<<2048, 256, 0, stream>>>(x, xb, 8388608 / 4);
    cvt_kernel<<<512, 256, 0, stream>>>(w_in, wib, 524288 / 4);
    cvt_kernel<<<1024, 256, 0, stream>>>(w_qkv, wqb, 3145728 / 4);
    cvt_kernel<<<1024, 256, 0, stream>>>(w_out, wob, 1048576 / 4);

    // GEMM1: x(16384x512) @ w_in^T -> x_proj bf16 (16384x1024)
    gemm_bt256<0><<<256, 512, 0, stream>>>(xb, wib, nullptr, xpb, nullptr, 1024, 512);
    // GEMM2: x_proj(16384x1024) @ w_qkv^T -> qkv (16384x3072), elu+1 on q,k
    gemm_bt256<1><<<768, 512, 0, stream>>>(xpb, wqb, nullptr, qkvb, nullptr, 3072, 1024);

    attn_kv<<<512, 256, 0, stream>>>(qkvb, kvp, ksp);
    attn_red<<<64, 256, 0, stream>>>(kvp, ksp, kvtb);
    attn_out_mfma<<<2048, 256, 0, stream>>>(qkvb, kvtb, attnb);

    // GEMM3: attn(16384x1024) @ w_out^T + x_proj -> out (f32)
    gemm_bt256<2><<<256, 512, 0, stream>>>(attnb, wob, out, nullptr, xpb, 1024, 1024);
    rms_kernel<<<16384, 256, 0, stream>>>(out, normw);
}

// Round 6
// 375.490 us; speedup vs baseline: 1.2883x; 1.0363x over previous
//
#include <hip/hip_runtime.h>
#include <stdint.h>

typedef unsigned short u16;
typedef unsigned int u32;

typedef __bf16 bf16_t;
typedef bf16_t bf16x8 __attribute__((ext_vector_type(8)));
typedef float f32x4 __attribute__((ext_vector_type(4)));

__device__ __forceinline__ u16 f2b(float f) {
    u32 u = __builtin_bit_cast(u32, f);
    u += 0x7FFFu + ((u >> 16) & 1u);   // RNE
    return (u16)(u >> 16);
}
__device__ __forceinline__ float b2f(u16 h) {
    return __builtin_bit_cast(float, (u32)h << 16);
}

__device__ __forceinline__ void gld_lds16(const void* gptr, void* lptr) {
    __builtin_amdgcn_global_load_lds(
        (const __attribute__((address_space(1))) void*)gptr,
        (__attribute__((address_space(3))) void*)lptr,
        16, 0, 0);
}

// ---------------- fused f32 -> bf16 conversion (4 segments) ----------------
__global__ __launch_bounds__(256) void cvt4_kernel(
    const float* __restrict__ s0, u16* __restrict__ d0, int n0,
    const float* __restrict__ s1, u16* __restrict__ d1, int n1,
    const float* __restrict__ s2, u16* __restrict__ d2, int n2,
    const float* __restrict__ s3, u16* __restrict__ d3, int n3)
{
    const int total = n0 + n1 + n2 + n3;
    int i = blockIdx.x * 256 + threadIdx.x;
    const int stride = gridDim.x * 256;
    for (; i < total; i += stride) {
        const float* s; u16* d; int j = i;
        if (j < n0) { s = s0; d = d0; }
        else if ((j -= n0) < n1) { s = s1; d = d1; }
        else if ((j -= n1) < n2) { s = s2; d = d2; }
        else { j -= n2; s = s3; d = d3; }
        float4 v = reinterpret_cast<const float4*>(s)[j];
        uint2 o;
        o.x = (u32)f2b(v.x) | ((u32)f2b(v.y) << 16);
        o.y = (u32)f2b(v.z) | ((u32)f2b(v.w) << 16);
        reinterpret_cast<uint2*>(d)[j] = o;
    }
}

// ======== 256x256 8-phase BT GEMM: C[M,N] = A[M,K]*B[N,K]^T, bf16, f32 acc ===
// 512 thr = 8 waves (2M x 4N); per-wave 128x64 out = 8 Mfrag x 4 Nfrag 16x16.
// LDS 128 KiB: AS[2][256][64] + BS[2][256][64] bf16; K-tile kt -> buf kt&1.
// 8 phases per 2 K-tiles; quadrant order (qm,qn)=(00,01,11,10) with fragment
// REGISTER REUSE across adjacent phases: LA/LB select which operand reloads
// (ph1: A+B, ph2: B, ph3: A, ph4: B -> 28KB LDS-read per K-tile per wave).
// Stage rotation fills just-freed halves; vmcnt(4) gates at ph4/ph8 only
// (vmcnt(0) at ph4 of the last iteration: no staging slack to cover kt1 halves).
#define PHASE(c, qm, qn, LA, LB, STAGES, GATE) do {                            \
    if (LA) {                                                                  \
        _Pragma("unroll") for (int ii = 0; ii < 4; ++ii) {                     \
            const int r = (qm)*128 + wm*64 + ii*16 + fr;                       \
            const char* pa = (const char*)AS[c] + r*128; const int rs=(r&7)<<4;\
            af[ii][0] = *(const bf16x8*)(pa + ((fk<<4)^rs));                   \
            af[ii][1] = *(const bf16x8*)(pa + ((64|(fk<<4))^rs)); } }          \
    if (LB) {                                                                  \
        _Pragma("unroll") for (int jj = 0; jj < 2; ++jj) {                     \
            const int r = (qn)*128 + wn*32 + jj*16 + fr;                       \
            const char* pb = (const char*)BS[c] + r*128; const int rs=(r&7)<<4;\
            bfv[jj][0] = *(const bf16x8*)(pb + ((fk<<4)^rs));                  \
            bfv[jj][1] = *(const bf16x8*)(pb + ((64|(fk<<4))^rs)); } }         \
    STAGES;                                                                    \
    __builtin_amdgcn_s_barrier();                                              \
    __builtin_amdgcn_s_setprio(1);                                             \
    _Pragma("unroll") for (int ks = 0; ks < 2; ++ks)                           \
      _Pragma("unroll") for (int ii = 0; ii < 4; ++ii)                         \
        _Pragma("unroll") for (int jj = 0; jj < 2; ++jj)                       \
            acc[(qm)*4+ii][(qn)*2+jj] = __builtin_amdgcn_mfma_f32_16x16x32_bf16( \
                af[ii][ks], bfv[jj][ks], acc[(qm)*4+ii][(qn)*2+jj], 0, 0, 0);  \
    __builtin_amdgcn_s_setprio(0);                                             \
    GATE;                                                                      \
    __builtin_amdgcn_s_barrier();                                              \
} while (0)

#define VGATE  asm volatile("s_waitcnt vmcnt(4)" ::: "memory")
#define VGATE0 asm volatile("s_waitcnt vmcnt(0)" ::: "memory")
#define NOGATE ((void)0)

template <int EPI>
__global__ __launch_bounds__(512) void gemm_bt256(
    const u16* __restrict__ A, const u16* __restrict__ Bw,
    float* __restrict__ outF, u16* __restrict__ outB,
    const u16* __restrict__ residB, int N, int K)
{
    __shared__ u16 AS[2][16384];   // [buf][256 rows][64 k]
    __shared__ u16 BS[2][16384];

    const int t = threadIdx.x;
    const int ntile = N >> 8;
    const int nwg = gridDim.x;
    const int wg = ((int)blockIdx.x & 7) * (nwg >> 3) + ((int)blockIdx.x >> 3);
    const int mt = wg / ntile;
    const int nt = wg - mt * ntile;
    const size_t brow = (size_t)mt << 8;
    const size_t bcol = (size_t)nt << 8;

    const int lane = t & 63, wv = t >> 6;
    const int wm = wv >> 2, wn = wv & 3;
    const int fr = lane & 15, fk = lane >> 4;
    const int nkt = K >> 6;
    const int niter = nkt >> 1;

    f32x4 acc[8][4] = {};
    bf16x8 af[4][2];    // persists across phases (A-frag reuse)
    bf16x8 bfv[2][2];   // persists across phases (B-frag reuse)

    // stage one half-tile (128 rows x 64 k = 16 KiB) of A or B into buf c
    auto STG = [&](int c, int half, int isA, int kt) {
        const u16* G = isA ? A : Bw;
        const size_t g0 = isA ? brow : bcol;
        u16* lds = isA ? AS[c] : BS[c];
        const int k0 = kt << 6;
#pragma unroll
        for (int j = 0; j < 2; ++j) {
            const int row = (half << 7) + (j << 6) + (t >> 3);
            const int kb = ((t & 7) << 4) ^ ((row & 7) << 4);  // inv-swizzled src
            gld_lds16(G + (g0 + row) * (size_t)K + k0 + (kb >> 1),
                      lds + row * 64 + (t & 7) * 8);           // linear dest
        }
    };

    // prologue: kt0 all 4 halves; kt1 Ah0+Bh1 (its Ah1/Bh0 come at ph1/ph2)
    STG(0, 0, 1, 0); STG(0, 1, 1, 0); STG(0, 0, 0, 0); STG(0, 1, 0, 0);
    STG(1, 0, 1, 1); STG(1, 1, 0, 1);
    asm volatile("s_waitcnt vmcnt(4)" ::: "memory");   // kt0 landed; kt1 pair in flight
    __builtin_amdgcn_s_barrier();

#pragma unroll 1
    for (int i = 0; i < niter; ++i) {
        const int kt1 = 2 * i + 1, kt2 = 2 * i + 2, kt3 = 2 * i + 3;
        const bool more = kt2 < nkt;
        PHASE(0, 0, 0, 1, 1, STG(1, 1, 1, kt1), NOGATE);                  // ph1
        PHASE(0, 0, 1, 0, 1, STG(1, 0, 0, kt1), NOGATE);                  // ph2
        PHASE(0, 1, 1, 1, 0, if (more) STG(0, 0, 1, kt2), NOGATE);        // ph3
        PHASE(0, 1, 0, 0, 1, if (more) STG(0, 1, 0, kt2),
              if (more) { VGATE; } else { VGATE0; });                     // ph4
        PHASE(1, 0, 0, 1, 1, if (more) STG(0, 1, 1, kt2), NOGATE);        // ph5
        PHASE(1, 0, 1, 0, 1, if (more) STG(0, 0, 0, kt2), NOGATE);        // ph6
        PHASE(1, 1, 1, 1, 0, if (more) STG(1, 0, 1, kt3), NOGATE);        // ph7
        PHASE(1, 1, 0, 0, 1, if (more) STG(1, 1, 0, kt3), VGATE);         // ph8
    }

    // C/D mapping: col = lane&15, row = (lane>>4)*4 + reg
    const int r0 = (lane >> 4) << 2;
    const int c0 = lane & 15;
#pragma unroll
    for (int f = 0; f < 8; ++f) {
        const size_t growb = brow + ((f >> 2) * 128 + wm * 64 + (f & 3) * 16 + r0);
#pragma unroll
        for (int r = 0; r < 4; ++r) {
            const size_t grow = growb + r;
#pragma unroll
            for (int g = 0; g < 4; ++g) {
                const size_t gcol = bcol + ((g >> 1) * 128 + wn * 32 + (g & 1) * 16) + c0;
                float v = acc[f][g][r];
                const size_t idx = grow * (size_t)N + gcol;
                if (EPI == 0) {
                    outB[idx] = f2b(v);
                } else if (EPI == 1) {
                    if (gcol < 2048) v = (v > 0.f) ? (v + 1.f) : __expf(v);  // elu+1
                    outB[idx] = f2b(v);
                } else {
                    outF[idx] = v + b2f(residB[idx]);
                }
            }
        }
    }
}

// ---------------- linear attention: partial kv (64x64) + ksum over L-split ----
__global__ __launch_bounds__(256) void attn_kv(
    const u16* __restrict__ qkvb, float* __restrict__ kvpart, float* __restrict__ kspart)
{
    __shared__ __align__(16) u16 kfs[2048];  // [32 l][64 d]
    __shared__ __align__(16) u16 vss[2048];
    __shared__ float ksp[4][64];
    const int t = threadIdx.x;
    const int bh = blockIdx.x >> 3;
    const int split = blockIdx.x & 7;
    const int b = bh >> 4, h = bh & 15;
    const size_t base = (size_t)b * (4096 * 3072) + h * 64;
    const int wv = t >> 6, lane = t & 63;
    const int lload = t >> 3, dload = (t & 7) << 3;
    const int dg = t >> 5;
    const int m0 = (t & 31) << 1;

    float acc[8][2] = {};
    float ks = 0.f;

    for (int c = 0; c < 512; c += 32) {
        __syncthreads();
        const size_t l = (size_t)split * 512 + c + lload;
        *(uint4*)(kfs + lload * 64 + dload) = *(const uint4*)(qkvb + base + l * 3072 + 1024 + dload);
        *(uint4*)(vss + lload * 64 + dload) = *(const uint4*)(qkvb + base + l * 3072 + 2048 + dload);
        __syncthreads();
#pragma unroll 4
        for (int ll = 0; ll < 32; ++ll) {
            const uint4 kfu = *(const uint4*)(kfs + ll * 64 + (dg << 3));
            const u32 vu = *(const u32*)(vss + ll * 64 + m0);
            const float v0 = __builtin_bit_cast(float, vu << 16);
            const float v1 = __builtin_bit_cast(float, vu & 0xFFFF0000u);
            const u32 kw[4] = {kfu.x, kfu.y, kfu.z, kfu.w};
#pragma unroll
            for (int p = 0; p < 4; ++p) {
                const float klo = __builtin_bit_cast(float, kw[p] << 16);
                const float khi = __builtin_bit_cast(float, kw[p] & 0xFFFF0000u);
                acc[2 * p][0]     += klo * v0;
                acc[2 * p][1]     += klo * v1;
                acc[2 * p + 1][0] += khi * v0;
                acc[2 * p + 1][1] += khi * v1;
            }
        }
        const int lb = wv << 3;
#pragma unroll
        for (int q = 0; q < 8; ++q) ks += b2f(kfs[(lb + q) * 64 + lane]);
    }
    ksp[wv][lane] = ks;
    const size_t obase = (size_t)blockIdx.x * 4096;
#pragma unroll
    for (int i = 0; i < 8; ++i) {
        float2 w = {acc[i][0], acc[i][1]};
        *(float2*)(kvpart + obase + (size_t)((dg << 3) + i) * 64 + m0) = w;
    }
    __syncthreads();
    if (t < 64)
        kspart[(size_t)blockIdx.x * 64 + t] = ksp[0][t] + ksp[1][t] + ksp[2][t] + ksp[3][t];
}

// ---------------- reduce 8 partials -> bf16 B-tile for attn_out ----------------
__global__ __launch_bounds__(256) void attn_red(
    const float* __restrict__ kvpart, const float* __restrict__ kspart,
    u16* __restrict__ kvtb)
{
    const int bh = blockIdx.x;
    const int t = threadIdx.x;
    const size_t pbase = (size_t)bh * 8 * 4096;
    u16* ob = kvtb + (size_t)bh * 6144;
#pragma unroll 2
    for (int rep = 0; rep < 16; ++rep) {
        const int e = rep * 256 + t;   // e = d*64 + m
        float s = 0.f;
#pragma unroll
        for (int p = 0; p < 8; ++p) s += kvpart[pbase + (size_t)p * 4096 + e];
        const int d = e >> 6, m = e & 63;
        ob[m * 64 + d] = f2b(s);       // transposed
    }
    if (t < 64) {
        float s = 0.f;
#pragma unroll
        for (int p = 0; p < 8; ++p) s += kspart[(size_t)(bh * 8 + p) * 64 + t];
        ob[64 * 64 + t] = f2b(s);
    }
    for (int z = t; z < 1984; z += 256) ob[65 * 64 + z] = 0;
}

// ---------------- attn_out via MFMA ----------------
__global__ __launch_bounds__(256) void attn_out_mfma(
    const u16* __restrict__ qkvb, const u16* __restrict__ kvtb,
    u16* __restrict__ attnb)
{
    __shared__ u16 As[8192];   // [128 l][64 d]
    __shared__ u16 Bs[6144];   // [96 m'][64 d]
    const int t = threadIdx.x;
    const int bh = blockIdx.x >> 5;
    const int lt = blockIdx.x & 31;
    const int b = bh >> 4, h = bh & 15;
    const size_t qbase = (size_t)b * (4096 * 3072) + h * 64;
    const int l0 = lt << 7;

    const int lane = t & 63;
    const int wv = t >> 6;
    const int fr = lane & 15;
    const int fk = lane >> 4;
    const int swz = (fr & 7) << 4;
    const int srow = t >> 3;
    const int pb = (t & 7) << 4;

#pragma unroll
    for (int i = 0; i < 4; ++i) {
        const int row = (i << 5) + srow;
        const int kb = pb ^ ((row & 7) << 4);
        gld_lds16(qkvb + qbase + (size_t)(l0 + row) * 3072 + (kb >> 1),
                  As + (i << 11) + t * 8);
    }
#pragma unroll
    for (int i = 0; i < 3; ++i) {
        const int row = (i << 5) + srow;
        const int kb = pb ^ ((row & 7) << 4);
        gld_lds16(kvtb + (size_t)bh * 6144 + row * 64 + (kb >> 1),
                  Bs + (i << 11) + t * 8);
    }
    __syncthreads();

    f32x4 acc[2][5] = {};
    const int wrow = wv << 5;
#pragma unroll
    for (int ks = 0; ks < 2; ++ks) {
        const int col = ((ks << 6) | (fk << 4)) ^ swz;
        bf16x8 af[2], bfr[5];
#pragma unroll
        for (int i = 0; i < 2; ++i)
            af[i] = *(const bf16x8*)((const char*)As + (wrow + (i << 4) + fr) * 128 + col);
#pragma unroll
        for (int j = 0; j < 5; ++j)
            bfr[j] = *(const bf16x8*)((const char*)Bs + ((j << 4) + fr) * 128 + col);
#pragma unroll
        for (int i = 0; i < 2; ++i)
#pragma unroll
            for (int j = 0; j < 5; ++j)
                acc[i][j] = __builtin_amdgcn_mfma_f32_16x16x32_bf16(
                    af[i], bfr[j], acc[i][j], 0, 0, 0);
    }

    const int r0 = (lane >> 4) << 2;
    const int c0 = lane & 15;
#pragma unroll
    for (int i = 0; i < 2; ++i) {
#pragma unroll
        for (int r = 0; r < 4; ++r) {
            const int row = wrow + (i << 4) + r0 + r;
            const float nv = __shfl(acc[i][4][r], lane & 48, 64);  // col 64 = nrm
            const float inv = 1.f / (nv + 1e-8f);
            const size_t obase = ((size_t)bh * 4096 + l0 + row) * 64;
#pragma unroll
            for (int j = 0; j < 4; ++j)
                attnb[obase + (j << 4) + c0] = f2b(acc[i][j][r] * inv);
        }
    }
}

// ---------------- RMS norm (in-place), one block per row of 1024 ----------------
__global__ __launch_bounds__(256) void rms_kernel(float* __restrict__ y,
                                                  const float* __restrict__ nw)
{
    __shared__ float red[4];
    const size_t row = blockIdx.x;
    const int t = threadIdx.x;
    float4 v = *(float4*)(y + row * 1024 + t * 4);
    float s = v.x * v.x + v.y * v.y + v.z * v.z + v.w * v.w;
#pragma unroll
    for (int off = 32; off > 0; off >>= 1) s += __shfl_down(s, off, 64);
    if ((t & 63) == 0) red[t >> 6] = s;
    __syncthreads();
    const float tot = red[0] + red[1] + red[2] + red[3];
    const float rms = rsqrtf(tot * (1.f / 1024.f) + 1.1920929e-7f);
    const float4 w = *(const float4*)(nw + t * 4);
    v.x *= rms * w.x; v.y *= rms * w.y; v.z *= rms * w.z; v.w *= rms * w.w;
    *(float4*)(y + row * 1024 + t * 4) = v;
}

extern "C" void kernel_launch(void* const* d_in, const int* in_sizes, int n_in,
                              void* d_out, int out_size, void* d_ws, size_t ws_size,
                              hipStream_t stream)
{
    const float* x     = (const float*)d_in[0];   // (4,4096,512)
    const float* w_in  = (const float*)d_in[1];   // (1024,512)
    const float* w_qkv = (const float*)d_in[2];   // (3072,1024)
    const float* w_out = (const float*)d_in[3];   // (1024,1024)
    const float* normw = (const float*)d_in[4];   // (1024,)
    float* out = (float*)d_out;                   // (4,4096,1024) f32

    char* ws = (char*)d_ws;
    size_t off = 0;
    auto alloc = [&](size_t bytes) {
        char* p = ws + off;
        off += (bytes + 255) & ~(size_t)255;
        return p;
    };
    // total ws usage ~193 MiB
    u16* xb    = (u16*)alloc(8388608ull * 2);    // x bf16                (16 MiB)
    u16* wib   = (u16*)alloc(524288ull * 2);     // w_in bf16             (1 MiB)
    u16* wqb   = (u16*)alloc(3145728ull * 2);    // w_qkv bf16            (6 MiB)
    u16* wob   = (u16*)alloc(1048576ull * 2);    // w_out bf16            (2 MiB)
    u16* xpb   = (u16*)alloc(16777216ull * 2);   // x_proj bf16           (32 MiB)
    u16* qkvb  = (u16*)alloc(50331648ull * 2);   // qf/kf/v bf16          (96 MiB)
    float* kvp = (float*)alloc(512ull * 4096 * 4);  // kv partials        (8 MiB)
    float* ksp = (float*)alloc(512ull * 64 * 4);    // ksum partials
    u16* kvtb  = (u16*)alloc(64ull * 96 * 64 * 2);  // kvT+ksum bf16 tile (768 KiB)
    u16* attnb = (u16*)alloc(16777216ull * 2);   // attn out bf16 == GEMM3 A (32 MiB)

    cvt4_kernel<<<2048, 256, 0, stream>>>(x, xb, 8388608 / 4,
                                          w_in, wib, 524288 / 4,
                                          w_qkv, wqb, 3145728 / 4,
                                          w_out, wob, 1048576 / 4);

    // GEMM1: x(16384x512) @ w_in^T -> x_proj bf16 (16384x1024)
    gemm_bt256<0><<<256, 512, 0, stream>>>(xb, wib, nullptr, xpb, nullptr, 1024, 512);
    // GEMM2: x_proj(16384x1024) @ w_qkv^T -> qkv (16384x3072), elu+1 on q,k
    gemm_bt256<1><<<768, 512, 0, stream>>>(xpb, wqb, nullptr, qkvb, nullptr, 3072, 1024);

    attn_kv<<<512, 256, 0, stream>>>(qkvb, kvp, ksp);
    attn_red<<<64, 256, 0, stream>>>(kvp, ksp, kvtb);
    attn_out_mfma<<<2048, 256, 0, stream>>>(qkvb, kvtb, attnb);

    // GEMM3: attn(16384x1024) @ w_out^T + x_proj -> out (f32)
    gemm_bt256<2><<<256, 512, 0, stream>>>(attnb, wob, out, nullptr, xpb, 1024, 1024);
    rms_kernel<<<16384, 256, 0, stream>>>(out, normw);
}